// Round 1
// baseline (192.213 us; speedup 1.0000x reference)
//
#include <hip/hip_runtime.h>
#include <hip/hip_bf16.h>

// DifferenceOfGaussians on MI355X.
// Pipeline: weights -> horizontal blur (fp64 acc) -> vertical blur + DoG
// (fp64 acc, fused pair) -> 3x3x3 peak detect (ballot bitmask per row) ->
// prefix-sum of row counts -> fill padding -> ordered emit.
//
// Workspace layout (bytes):
//   OFF_W    : double w[14][96]           (1D normalized Gaussian weights)
//   OFF_RAD  : int    rad[14]
//   OFF_H    : float  h[14][512][512]     (horizontal pass)
//   OFF_DOG  : float  dog[13][512][512]
//   OFF_BITS : u64    rowbits[6656][8]    (peak bitmask per (s,y) row)
//   OFF_RCNT : int    rowcount[6656]
//   OFF_ROFF : int    rowoff[6656]        (exclusive prefix)
// total ~28.8 MB

#define OFF_W    0
#define OFF_RAD  10752
#define OFF_H    16384
#define OFF_DOG  (16384 + 14680064)              // 14696448
#define OFF_BITS (14696448 + 13631488)           // 28327936
#define OFF_RCNT (28327936 + 425984)             // 28753920
#define OFF_ROFF (28753920 + 26624)              // 28780544

#define NSIG 13          // number of DoG planes
#define NROWS (13 * 512)
#define MAXPEAKS 32768

// ---- 1: per-sigma 1D normalized weights (fp64) ----
__global__ __launch_bounds__(128) void wkern(const float* __restrict__ sigma_list,
                                             double* __restrict__ w,
                                             int* __restrict__ rad) {
    int i = blockIdx.x;                 // 0..13
    float s = sigma_list[i];
    int r = (int)(4.0f * s + 0.5f);     // matches int(TRUNCATE*s + 0.5)
    int n = 2 * r + 1;
    double sd = (double)s;
    int t = threadIdx.x;
    double val = 0.0;
    if (t < n) {
        double d = (double)(t - r);
        double q = d / (2.0 * sd);      // reference uses exp(-(d/(2s))^2)
        val = exp(-q * q);
    }
    __shared__ double sh[128];
    sh[t] = val;
    __syncthreads();
    for (int off = 64; off > 0; off >>= 1) {
        if (t < off) sh[t] += sh[t + off];
        __syncthreads();
    }
    double sum = sh[0];
    if (t < n) w[i * 96 + t] = val / sum;
    if (t == 0) rad[i] = r;
}

// ---- 2: horizontal blur, zero-padded, fp64 accumulate, store f32 ----
__global__ __launch_bounds__(256) void hpass(const float* __restrict__ x,
                                             const double* __restrict__ w,
                                             const int* __restrict__ rad,
                                             float* __restrict__ h) {
    int i = blockIdx.y;                 // sigma 0..13
    int y = blockIdx.x;                 // row 0..511
    int t = threadIdx.x;
    __shared__ float row[512];
    __shared__ double wl[87];
    int r = rad[i];
    row[t]       = x[y * 512 + t];
    row[t + 256] = x[y * 512 + t + 256];
    if (t < 2 * r + 1) wl[t] = w[i * 96 + t];
    __syncthreads();
    for (int xx = t; xx < 512; xx += 256) {
        int dlo = -min(r, xx);
        int dhi =  min(r, 511 - xx);
        double acc = 0.0;
        for (int d = dlo; d <= dhi; ++d)
            acc = fma(wl[d + r], (double)row[xx + d], acc);
        h[(i * 512 + y) * 512 + xx] = (float)acc;
    }
}

// ---- 3: vertical blur for sigma i and i+1, fused DoG ----
__global__ __launch_bounds__(512) void vdog(const float* __restrict__ h,
                                            const double* __restrict__ w,
                                            const int* __restrict__ rad,
                                            const float* __restrict__ sigma_list,
                                            float* __restrict__ dog) {
    int di = blockIdx.y;                // DoG plane 0..12
    int y  = blockIdx.x;                // 0..511
    int t  = threadIdx.x;               // x
    __shared__ double w0[87], w1[87];
    int r0 = rad[di], r1 = rad[di + 1];
    if (t < 2 * r0 + 1) w0[t] = w[di * 96 + t];
    if (t < 2 * r1 + 1) w1[t] = w[(di + 1) * 96 + t];
    __syncthreads();
    const float* h0 = h + di * 262144;
    const float* h1 = h0 + 262144;
    double acc0 = 0.0, acc1 = 0.0;
    {
        int dlo = -min(r0, y), dhi = min(r0, 511 - y);
        for (int d = dlo; d <= dhi; ++d)
            acc0 = fma(w0[d + r0], (double)h0[(y + d) * 512 + t], acc0);
    }
    {
        int dlo = -min(r1, y), dhi = min(r1, 511 - y);
        for (int d = dlo; d <= dhi; ++d)
            acc1 = fma(w1[d + r1], (double)h1[(y + d) * 512 + t], acc1);
    }
    double sg = (double)sigma_list[di];
    dog[(di * 512 + y) * 512 + t] = (float)((acc0 - acc1) * sg);
}

// ---- 4: 3x3x3 strict-interior local-max detect; ballot into rowbits ----
__global__ __launch_bounds__(512) void detect(const float* __restrict__ dog,
                                              unsigned long long* __restrict__ rowbits,
                                              int* __restrict__ rowcount) {
    int bz = blockIdx.x;                // (s,y) row: 0..6655
    int s = bz >> 9;
    int y = bz & 511;
    int x = threadIdx.x;
    float v = dog[(s * 512 + y) * 512 + x];
    bool peak = false;
    if (s >= 1 && s <= 11 && y >= 1 && y <= 510 && x >= 1 && x <= 510 && v > 0.001f) {
        peak = true;
        for (int ds = -1; ds <= 1 && peak; ++ds)
            for (int dy = -1; dy <= 1 && peak; ++dy)
                for (int dx = -1; dx <= 1; ++dx) {
                    if ((ds | dy | dx) == 0) continue;
                    if (v < dog[((s + ds) * 512 + (y + dy)) * 512 + (x + dx)]) {
                        peak = false;
                        break;
                    }
                }
    }
    unsigned long long m = __ballot(peak);
    int wid = x >> 6, lane = x & 63;
    __shared__ int cnt[8];
    if (lane == 0) {
        rowbits[bz * 8 + wid] = m;
        cnt[wid] = __popcll(m);
    }
    __syncthreads();
    if (x == 0) {
        int c = 0;
        for (int k = 0; k < 8; ++k) c += cnt[k];
        rowcount[bz] = c;
    }
}

// ---- 5: exclusive prefix sum over 6656 row counts (single block) ----
__global__ __launch_bounds__(1024) void scan(const int* __restrict__ rowcount,
                                             int* __restrict__ rowoff) {
    const int CH = 7;                   // 1024*7 >= 6656
    int t = threadIdx.x;
    int base = t * CH;
    int local[CH];
    int s = 0;
    for (int k = 0; k < CH; ++k) {
        int idx = base + k;
        int c = (idx < NROWS) ? rowcount[idx] : 0;
        local[k] = s;                   // exclusive within chunk
        s += c;
    }
    __shared__ int part[1024];
    part[t] = s;
    __syncthreads();
    for (int off = 1; off < 1024; off <<= 1) {
        int val = part[t];
        int add = (t >= off) ? part[t - off] : 0;
        __syncthreads();
        part[t] = val + add;
        __syncthreads();
    }
    int chunkbase = part[t] - s;        // exclusive chunk base
    for (int k = 0; k < CH; ++k) {
        int idx = base + k;
        if (idx < NROWS) rowoff[idx] = chunkbase + local[k];
    }
}

// ---- 6: fill all output rows with padding pattern (sigma0, 0, 0) ----
__global__ __launch_bounds__(256) void fillpad(float* __restrict__ out,
                                               const float* __restrict__ sigma_list) {
    int j = blockIdx.x * blockDim.x + threadIdx.x;
    if (j < MAXPEAKS) {
        float s0 = sigma_list[0];
        out[j * 3 + 0] = s0;
        out[j * 3 + 1] = 0.0f;
        out[j * 3 + 2] = 0.0f;
    }
}

// ---- 7: ordered emit from bitmasks + row offsets ----
__global__ __launch_bounds__(512) void emit(const unsigned long long* __restrict__ rowbits,
                                            const int* __restrict__ rowoff,
                                            const float* __restrict__ sigma_list,
                                            float* __restrict__ out) {
    int bz = blockIdx.x;
    int s = bz >> 9;
    int y = bz & 511;
    int t = threadIdx.x;
    __shared__ unsigned long long m[8];
    __shared__ int roff;
    if (t < 8) m[t] = rowbits[bz * 8 + t];
    if (t == 0) roff = rowoff[bz];
    __syncthreads();
    int wid = t >> 6, lane = t & 63;
    unsigned long long mw = m[wid];
    if ((mw >> lane) & 1ull) {
        int rank = 0;
        for (int k = 0; k < wid; ++k) rank += __popcll(m[k]);
        rank += __popcll(mw & ((1ull << lane) - 1ull));
        int pos = roff + rank;
        if (pos < MAXPEAKS) {
            out[pos * 3 + 0] = sigma_list[s];
            out[pos * 3 + 1] = (float)y;
            out[pos * 3 + 2] = (float)t;
        }
    }
}

extern "C" void kernel_launch(void* const* d_in, const int* in_sizes, int n_in,
                              void* d_out, int out_size, void* d_ws, size_t ws_size,
                              hipStream_t stream) {
    const float* x     = (const float*)d_in[0];   // [1,1,512,512]
    // d_in[1] = weight [14,1,87,87] (unused; we rebuild separable 1D weights)
    const float* sigma = (const float*)d_in[2];   // [14]
    float* out = (float*)d_out;                   // [32768,3]

    char* ws = (char*)d_ws;
    double* w                    = (double*)(ws + OFF_W);
    int* rad                     = (int*)(ws + OFF_RAD);
    float* h                     = (float*)(ws + OFF_H);
    float* dog                   = (float*)(ws + OFF_DOG);
    unsigned long long* rowbits  = (unsigned long long*)(ws + OFF_BITS);
    int* rowcount                = (int*)(ws + OFF_RCNT);
    int* rowoff                  = (int*)(ws + OFF_ROFF);

    wkern<<<14, 128, 0, stream>>>(sigma, w, rad);
    hpass<<<dim3(512, 14), 256, 0, stream>>>(x, w, rad, h);
    vdog<<<dim3(512, NSIG), 512, 0, stream>>>(h, w, rad, sigma, dog);
    detect<<<NROWS, 512, 0, stream>>>(dog, rowbits, rowcount);
    scan<<<1, 1024, 0, stream>>>(rowcount, rowoff);
    fillpad<<<(MAXPEAKS + 255) / 256, 256, 0, stream>>>(out, sigma);
    emit<<<NROWS, 512, 0, stream>>>(rowbits, rowoff, sigma, out);
}

// Round 2
// 167.761 us; speedup vs baseline: 1.1458x; 1.1458x over previous
//
#include <hip/hip_runtime.h>
#include <hip/hip_bf16.h>

// DifferenceOfGaussians on MI355X — round 2.
// Register-blocked separable Gaussian pyramid (fp64 acc), fused DoG,
// LDS-staged 3x3x3 peak detect, ordered emit via ballot + prefix sum.
//
// Workspace layout (bytes):
//   OFF_W    : double w[14][96]
//   OFF_RAD  : int    rad[14]
//   OFF_H    : float  h[14][512][512]
//   OFF_DOG  : float  dog[13][512][512]
//   OFF_BITS : u64    rowbits[6656][8]
//   OFF_RCNT : int    rowcount[6656]
//   OFF_ROFF : int    rowoff[6656]

#define OFF_W    0
#define OFF_RAD  10752
#define OFF_H    16384
#define OFF_DOG  (16384 + 14680064)              // 14696448
#define OFF_BITS (14696448 + 13631488)           // 28327936
#define OFF_RCNT (28327936 + 425984)             // 28753920
#define OFF_ROFF (28753920 + 26624)              // 28780544

#define NSIG 13
#define NROWS (13 * 512)
#define MAXPEAKS 32768
#define NJ 16            // outputs per thread in vdog (vertical register tile)

// ---- 1: per-sigma 1D normalized weights (fp64) ----
__global__ __launch_bounds__(128) void wkern(const float* __restrict__ sigma_list,
                                             double* __restrict__ w,
                                             int* __restrict__ rad) {
    int i = blockIdx.x;
    float s = sigma_list[i];
    int r = (int)(4.0f * s + 0.5f);
    int n = 2 * r + 1;
    double sd = (double)s;
    int t = threadIdx.x;
    double val = 0.0;
    if (t < n) {
        double d = (double)(t - r);
        double q = d / (2.0 * sd);
        val = exp(-q * q);
    }
    __shared__ double sh[128];
    sh[t] = val;
    __syncthreads();
    for (int off = 64; off > 0; off >>= 1) {
        if (t < off) sh[t] += sh[t + off];
        __syncthreads();
    }
    double sum = sh[0];
    if (t < n) w[i * 96 + t] = val / sum;
    if (t == 0) rad[i] = r;
}

// ---- 2: horizontal blur; padded fp64 row in LDS; 4 px/thread ----
__global__ __launch_bounds__(128) void hpass(const float* __restrict__ x,
                                             const double* __restrict__ w,
                                             const int* __restrict__ rad,
                                             float* __restrict__ h) {
    int i = blockIdx.y;                 // sigma 0..13
    int y = blockIdx.x;                 // row 0..511
    int t = threadIdx.x;                // 0..127
    __shared__ double rowp[598];        // 43-wide zero pad both sides
    __shared__ double wl[87];
    int r = rad[i];
    for (int k = t; k < 598; k += 128) {
        int gx = k - 43;
        rowp[k] = ((unsigned)gx < 512u) ? (double)x[y * 512 + gx] : 0.0;
    }
    for (int k = t; k < 2 * r + 1; k += 128) wl[k] = w[i * 96 + k];
    __syncthreads();
    double a0 = 0.0, a1 = 0.0, a2 = 0.0, a3 = 0.0;
    int base = 43 + t - r;              // rowp idx of tap d for out pixel t
    for (int d = 0; d <= 2 * r; ++d) {
        double wd = wl[d];
        a0 = fma(wd, rowp[base + d], a0);
        a1 = fma(wd, rowp[base + 128 + d], a1);
        a2 = fma(wd, rowp[base + 256 + d], a2);
        a3 = fma(wd, rowp[base + 384 + d], a3);
    }
    float* hp = h + (i * 512 + y) * 512;
    hp[t]       = (float)a0;
    hp[t + 128] = (float)a1;
    hp[t + 256] = (float)a2;
    hp[t + 384] = (float)a3;
}

__device__ __forceinline__ double ldrow(const float* __restrict__ p, int row, int x) {
    return ((unsigned)row < 512u) ? (double)p[row * 512 + x] : 0.0;
}

// ---- 3: vertical blur pair + DoG; 16-row register tile, sliding window ----
__global__ __launch_bounds__(256) void vdog(const float* __restrict__ h,
                                            const double* __restrict__ w,
                                            const int* __restrict__ rad,
                                            const float* __restrict__ sigma_list,
                                            float* __restrict__ dog) {
    int di = blockIdx.z;                         // DoG plane 0..12
    int x  = blockIdx.x * 64 + (threadIdx.x & 63);
    int ysub = threadIdx.x >> 6;                 // 0..3
    int y0 = blockIdx.y * 64 + ysub * NJ;        // 16-row tile base
    int t = threadIdx.x;
    __shared__ double w0l[87], w1l[87];
    int r0 = rad[di], r1 = rad[di + 1];
    if (t < 2 * r0 + 1) w0l[t] = w[di * 96 + t];
    if (t < 2 * r1 + 1) w1l[t] = w[(di + 1) * 96 + t];
    __syncthreads();
    const float* h0 = h + di * 262144;
    const float* h1 = h0 + 262144;

    double acc[NJ];
#pragma unroll
    for (int j = 0; j < NJ; ++j) acc[j] = 0.0;

    {   // plane di: +w0
        double win[NJ];
#pragma unroll
        for (int j = 0; j < NJ - 1; ++j) win[j] = ldrow(h0, y0 - r0 + j, x);
        win[NJ - 1] = 0.0;
        for (int d = 0; d <= 2 * r0; ++d) {
            win[NJ - 1] = ldrow(h0, y0 - r0 + d + NJ - 1, x);
            double wd = w0l[d];
#pragma unroll
            for (int j = 0; j < NJ; ++j) acc[j] = fma(wd, win[j], acc[j]);
#pragma unroll
            for (int j = 0; j < NJ - 1; ++j) win[j] = win[j + 1];
        }
    }
    {   // plane di+1: -w1
        double win[NJ];
#pragma unroll
        for (int j = 0; j < NJ - 1; ++j) win[j] = ldrow(h1, y0 - r1 + j, x);
        win[NJ - 1] = 0.0;
        for (int d = 0; d <= 2 * r1; ++d) {
            win[NJ - 1] = ldrow(h1, y0 - r1 + d + NJ - 1, x);
            double wd = w1l[d];
#pragma unroll
            for (int j = 0; j < NJ; ++j) acc[j] = fma(-wd, win[j], acc[j]);
#pragma unroll
            for (int j = 0; j < NJ - 1; ++j) win[j] = win[j + 1];
        }
    }
    double sg = (double)sigma_list[di];
    float* dp = dog + (di * 512 + y0) * 512 + x;
#pragma unroll
    for (int j = 0; j < NJ; ++j) dp[j * 512] = (float)(acc[j] * sg);
}

// ---- 4: 3x3x3 peak detect, 9 rows staged in LDS; ballot into rowbits ----
__global__ __launch_bounds__(512) void detect(const float* __restrict__ dog,
                                              unsigned long long* __restrict__ rowbits,
                                              int* __restrict__ rowcount) {
    int bz = blockIdx.x;                // (s,y): 0..6655
    int s = bz >> 9;
    int y = bz & 511;
    int x = threadIdx.x;
    int wid = x >> 6, lane = x & 63;
    __shared__ float sh[9][512];
    __shared__ int cnt[8];
    bool interior = (s >= 1 && s <= 11 && y >= 1 && y <= 510);  // block-uniform
    if (interior) {
#pragma unroll
        for (int q = 0; q < 9; ++q) {
            int ds = q / 3 - 1, dy = q % 3 - 1;
            sh[q][x] = dog[((s + ds) * 512 + (y + dy)) * 512 + x];
        }
        __syncthreads();
        float v = sh[4][x];             // ds=0, dy=0
        bool peak = false;
        if (x >= 1 && x <= 510 && v > 0.001f) {
            float mx = -1e30f;
#pragma unroll
            for (int q = 0; q < 9; ++q)
                mx = fmaxf(mx, fmaxf(sh[q][x - 1], fmaxf(sh[q][x], sh[q][x + 1])));
            peak = (v >= mx);           // v participates in mx, so == max
        }
        unsigned long long m = __ballot(peak);
        if (lane == 0) {
            rowbits[bz * 8 + wid] = m;
            cnt[wid] = __popcll(m);
        }
    } else {
        if (x < 8) {
            rowbits[bz * 8 + x] = 0ull;
            cnt[x] = 0;
        }
    }
    __syncthreads();
    if (x == 0) {
        int c = 0;
        for (int k = 0; k < 8; ++k) c += cnt[k];
        rowcount[bz] = c;
    }
}

// ---- 5: exclusive prefix sum over 6656 row counts (single block) ----
__global__ __launch_bounds__(1024) void scan(const int* __restrict__ rowcount,
                                             int* __restrict__ rowoff) {
    const int CH = 7;
    int t = threadIdx.x;
    int base = t * CH;
    int local[CH];
    int s = 0;
    for (int k = 0; k < CH; ++k) {
        int idx = base + k;
        int c = (idx < NROWS) ? rowcount[idx] : 0;
        local[k] = s;
        s += c;
    }
    __shared__ int part[1024];
    part[t] = s;
    __syncthreads();
    for (int off = 1; off < 1024; off <<= 1) {
        int val = part[t];
        int add = (t >= off) ? part[t - off] : 0;
        __syncthreads();
        part[t] = val + add;
        __syncthreads();
    }
    int chunkbase = part[t] - s;
    for (int k = 0; k < CH; ++k) {
        int idx = base + k;
        if (idx < NROWS) rowoff[idx] = chunkbase + local[k];
    }
}

// ---- 6: fill all output rows with padding pattern (sigma0, 0, 0) ----
__global__ __launch_bounds__(256) void fillpad(float* __restrict__ out,
                                               const float* __restrict__ sigma_list) {
    int j = blockIdx.x * blockDim.x + threadIdx.x;
    if (j < MAXPEAKS) {
        float s0 = sigma_list[0];
        out[j * 3 + 0] = s0;
        out[j * 3 + 1] = 0.0f;
        out[j * 3 + 2] = 0.0f;
    }
}

// ---- 7: ordered emit from bitmasks + row offsets ----
__global__ __launch_bounds__(512) void emit(const unsigned long long* __restrict__ rowbits,
                                            const int* __restrict__ rowoff,
                                            const float* __restrict__ sigma_list,
                                            float* __restrict__ out) {
    int bz = blockIdx.x;
    int s = bz >> 9;
    int y = bz & 511;
    int t = threadIdx.x;
    __shared__ unsigned long long m[8];
    __shared__ int roff;
    if (t < 8) m[t] = rowbits[bz * 8 + t];
    if (t == 0) roff = rowoff[bz];
    __syncthreads();
    int wid = t >> 6, lane = t & 63;
    unsigned long long mw = m[wid];
    if ((mw >> lane) & 1ull) {
        int rank = 0;
        for (int k = 0; k < wid; ++k) rank += __popcll(m[k]);
        rank += __popcll(mw & ((1ull << lane) - 1ull));
        int pos = roff + rank;
        if (pos < MAXPEAKS) {
            out[pos * 3 + 0] = sigma_list[s];
            out[pos * 3 + 1] = (float)y;
            out[pos * 3 + 2] = (float)t;
        }
    }
}

extern "C" void kernel_launch(void* const* d_in, const int* in_sizes, int n_in,
                              void* d_out, int out_size, void* d_ws, size_t ws_size,
                              hipStream_t stream) {
    const float* x     = (const float*)d_in[0];   // [1,1,512,512]
    const float* sigma = (const float*)d_in[2];   // [14]
    float* out = (float*)d_out;                   // [32768,3]

    char* ws = (char*)d_ws;
    double* w                    = (double*)(ws + OFF_W);
    int* rad                     = (int*)(ws + OFF_RAD);
    float* h                     = (float*)(ws + OFF_H);
    float* dog                   = (float*)(ws + OFF_DOG);
    unsigned long long* rowbits  = (unsigned long long*)(ws + OFF_BITS);
    int* rowcount                = (int*)(ws + OFF_RCNT);
    int* rowoff                  = (int*)(ws + OFF_ROFF);

    wkern<<<14, 128, 0, stream>>>(sigma, w, rad);
    hpass<<<dim3(512, 14), 128, 0, stream>>>(x, w, rad, h);
    vdog<<<dim3(8, 8, NSIG), 256, 0, stream>>>(h, w, rad, sigma, dog);
    detect<<<NROWS, 512, 0, stream>>>(dog, rowbits, rowcount);
    scan<<<1, 1024, 0, stream>>>(rowcount, rowoff);
    fillpad<<<(MAXPEAKS + 255) / 256, 256, 0, stream>>>(out, sigma);
    emit<<<NROWS, 512, 0, stream>>>(rowbits, rowoff, sigma, out);
}

// Round 3
// 139.174 us; speedup vs baseline: 1.3811x; 1.2054x over previous
//
#include <hip/hip_runtime.h>
#include <hip/hip_bf16.h>

// DifferenceOfGaussians on MI355X — round 3.
// Rotating-register-window separable Gaussian (fp64 acc, zero-padded weight
// chunks of 16 => no window-shift moves, 1-stage load prefetch), heavy-plane-
// first dispatch, fused DoG, y-tiled colmax peak detect, ordered emit.
//
// Workspace (bytes):
//   OFF_H    : float h[14][512][512]      = 14,680,064
//   OFF_DOG  : float dog[13][512][512]    = 13,631,488
//   OFF_BITS : u64  rowbits[6656][8]      =    425,984
//   OFF_RCNT : int  rowcount[6656]
//   OFF_ROFF : int  rowoff[6657]          (last slot = grand total)
// total ~28.79 MB (<= proven 28.8 MB budget)

#define OFF_H    0
#define OFF_DOG  14680064
#define OFF_BITS 28311552
#define OFF_RCNT 28737536
#define OFF_ROFF 28764160

#define NSIG 13
#define NROWS (13 * 512)
#define MAXPEAKS 32768

// ---- 1: horizontal blur; skewed LDS row staging; 16 outputs/thread ----
// block 256 = 8 rows x 32 threads; grid (64 rowgroups, 14 planes), heavy first
__global__ __launch_bounds__(256) void hpass(const float* __restrict__ x,
                                             const float* __restrict__ sigma_list,
                                             float* __restrict__ h) {
    const int i = 13 - blockIdx.y;        // heavy plane dispatched first
    const int t = threadIdx.x;
    float s = sigma_list[i];
    int r = (int)(4.0f * s + 0.5f);       // int(TRUNCATE*s + 0.5)
    int n = 2 * r + 1;
    int nceil = (n + 15) & ~15;

    // in-block weight build (fp64), zero-padded to 96
    __shared__ double wl[96];
    __shared__ double red[128];
    double v = 0.0;
    if (t < 128) {
        if (t < n) {
            double d = (double)(t - r);
            double q = d / (2.0 * (double)s);   // reference: exp(-(d/(2s))^2)
            v = exp(-q * q);
        }
        red[t] = v;
    }
    __syncthreads();
    for (int off = 64; off > 0; off >>= 1) {
        if (t < off) red[t] += red[t + off];
        __syncthreads();
    }
    double wsum = red[0];
    if (t < 96) wl[t] = v / wsum;         // v==0 for t>=n -> zero pad

    // stage 8 zero-padded rows as skewed float (addr = p + p/16 -> stride 17)
    __shared__ float rowp[8][648];
    int y8 = blockIdx.x * 8;
    for (int rr = 0; rr < 8; ++rr)
        for (int k = t; k < 608; k += 256) {
            int gx = k - 43;
            float val = ((unsigned)gx < 512u) ? x[(y8 + rr) * 512 + gx] : 0.0f;
            rowp[rr][k + (k >> 4)] = val;
        }
    __syncthreads();

    int tsub = t & 31, row = t >> 5;
    int xb = tsub * 16;
    int P0 = 43 - r + xb;                 // p in [0,607] for all planes
    double acc[16], win[16];
#pragma unroll
    for (int j = 0; j < 16; ++j) acc[j] = 0.0;
#pragma unroll
    for (int sl = 0; sl < 16; ++sl) {
        int p = P0 + sl;
        win[sl] = (double)rowp[row][p + (p >> 4)];
    }
    for (int dc = 0; dc < nceil; dc += 16) {
#pragma unroll
        for (int k = 0; k < 16; ++k) {
            double wd = wl[dc + k];
#pragma unroll
            for (int j = 0; j < 16; ++j)
                acc[j] = fma(wd, win[(k + j) & 15], acc[j]);
            int p = P0 + dc + k + 16;     // reload slot k for next chunk
            win[k] = (double)rowp[row][p + (p >> 4)];
        }
    }
    float* hp = h + (i * 512 + (y8 + row)) * 512 + xb;
#pragma unroll
    for (int j = 0; j < 16; ++j) hp[j] = (float)acc[j];
}

// ---- helpers for vdog ----
__device__ __forceinline__ void make_w(const float* __restrict__ sigma_list,
                                       int plane, double sgn, double* wl,
                                       int lane, int* r_out, int* nc_out) {
    float s = sigma_list[plane];
    int r = (int)(4.0f * s + 0.5f);
    int n = 2 * r + 1;
    double v0 = 0.0, v1 = 0.0;
    {
        double sd = (double)s;
        if (lane < n) {
            double d = (double)(lane - r), q = d / (2.0 * sd);
            v0 = exp(-q * q);
        }
        if (lane + 64 < n) {
            double d = (double)(lane + 64 - r), q = d / (2.0 * sd);
            v1 = exp(-q * q);
        }
    }
    double part = v0 + v1;
    for (int m = 1; m < 64; m <<= 1) part += __shfl_xor(part, m);
    double inv = sgn / part;
    wl[lane] = v0 * inv;
    if (lane + 64 < 96) wl[lane + 64] = v1 * inv;   // zero pad to 96
    *r_out = r;
    *nc_out = (n + 15) & ~15;
}

__device__ __forceinline__ void conv_acc(const float* __restrict__ p, int x, int y0,
                                         int r, int nceil, const double* __restrict__ wl,
                                         double (&acc)[16]) {
    int Y0 = y0 - r;
    double win[16];
#pragma unroll
    for (int sl = 0; sl < 16; ++sl) {
        int yy = Y0 + sl;
        win[sl] = ((unsigned)yy < 512u) ? (double)p[yy * 512 + x] : 0.0;
    }
    for (int dc = 0; dc < nceil; dc += 16) {
#pragma unroll
        for (int k = 0; k < 16; ++k) {
            double wd = wl[dc + k];
#pragma unroll
            for (int j = 0; j < 16; ++j)
                acc[j] = fma(wd, win[(k + j) & 15], acc[j]);
            int yy = Y0 + dc + k + 16;
            win[k] = ((unsigned)yy < 512u) ? (double)p[yy * 512 + x] : 0.0;
        }
    }
}

// ---- 2: vertical blur pair + DoG; 1-wave blocks, heavy plane first ----
// grid (8 x-tiles, 32 y-tiles, 13 planes) = 3328 blocks of 64 threads
__global__ __launch_bounds__(64) void vdog(const float* __restrict__ h,
                                           const float* __restrict__ sigma_list,
                                           float* __restrict__ dog) {
    const int di = 12 - blockIdx.z;       // heaviest pair first
    const int lane = threadIdx.x;
    const int x = blockIdx.x * 64 + lane;
    const int y0 = blockIdx.y * 16;
    __shared__ double wl0[96], wl1[96];
    int r0, nc0, r1, nc1;
    make_w(sigma_list, di,     +1.0, wl0, lane, &r0, &nc0);
    make_w(sigma_list, di + 1, -1.0, wl1, lane, &r1, &nc1);   // negated
    __syncthreads();
    double acc[16];
#pragma unroll
    for (int j = 0; j < 16; ++j) acc[j] = 0.0;
    const float* hp0 = h + di * 262144;
    conv_acc(hp0,          x, y0, r0, nc0, wl0, acc);
    conv_acc(hp0 + 262144, x, y0, r1, nc1, wl1, acc);
    double sg = (double)sigma_list[di];
    float* dp = dog + (di * 512 + y0) * 512 + x;
#pragma unroll
    for (int j = 0; j < 16; ++j) dp[j * 512] = (float)(acc[j] * sg);
}

// ---- 3: 3x3x3 peak detect; y-tile of 8, colmax LDS trick ----
// grid (64 y-tiles, 13 scales), block 512
__global__ __launch_bounds__(512) void detect(const float* __restrict__ dog,
                                              unsigned long long* __restrict__ rowbits,
                                              int* __restrict__ rowcount) {
    const int s = blockIdx.y;             // 0..12
    const int y0 = blockIdx.x * 8;
    const int t = threadIdx.x;            // x
    const int w = t >> 6, lane = t & 63;

    if (s == 0 || s == 12) {              // scale border: no peaks
        if (t < 64) rowbits[(s * 512 + y0 + (t >> 3)) * 8 + (t & 7)] = 0ull;
        if (t < 8) rowcount[s * 512 + y0 + t] = 0;
        return;
    }

    float pm[10];                          // per-column max over 3 scales
    float vcen[8];
#pragma unroll
    for (int k = 0; k < 8; ++k) vcen[k] = 0.0f;
#pragma unroll
    for (int q = 0; q < 10; ++q) {
        int yy = y0 - 1 + q;
        float m = -3.0e38f;
        if ((unsigned)yy < 512u) {
            float a = dog[((s - 1) * 512 + yy) * 512 + t];
            float b = dog[(s * 512 + yy) * 512 + t];
            float c = dog[((s + 1) * 512 + yy) * 512 + t];
            m = fmaxf(a, fmaxf(b, c));
            if (q >= 1 && q <= 8) vcen[q - 1] = b;
        }
        pm[q] = m;
    }
    __shared__ float cml[8][512];
    __shared__ int cnt[8][8];
#pragma unroll
    for (int k = 0; k < 8; ++k)
        cml[k][t] = fmaxf(pm[k], fmaxf(pm[k + 1], pm[k + 2]));
    __syncthreads();
#pragma unroll
    for (int k = 0; k < 8; ++k) {
        int y = y0 + k;
        bool peak = false;
        if (t >= 1 && t <= 510 && y >= 1 && y <= 510) {
            float v = vcen[k];
            if (v > 0.001f) {
                float mx = fmaxf(cml[k][t - 1], fmaxf(cml[k][t], cml[k][t + 1]));
                peak = (v >= mx);         // mx includes v -> v == window max
            }
        }
        unsigned long long m = __ballot(peak);
        if (lane == 0) {
            rowbits[(s * 512 + y) * 8 + w] = m;
            cnt[k][w] = __popcll(m);
        }
    }
    __syncthreads();
    if (t < 8) {
        int c = 0;
#pragma unroll
        for (int q = 0; q < 8; ++q) c += cnt[t][q];
        rowcount[s * 512 + y0 + t] = c;
    }
}

// ---- 4: exclusive prefix sum over 6656 row counts; writes total ----
__global__ __launch_bounds__(256) void scan(const int* __restrict__ rowcount,
                                            int* __restrict__ rowoff) {
    const int CH = 26;                    // 256*26 == 6656 exactly
    int t = threadIdx.x;
    int base = t * CH;
    int local[CH];
    int s = 0;
    for (int k = 0; k < CH; ++k) {
        int c = rowcount[base + k];
        local[k] = s;
        s += c;
    }
    __shared__ int part[256];
    part[t] = s;
    __syncthreads();
    for (int off = 1; off < 256; off <<= 1) {
        int val = part[t];
        int add = (t >= off) ? part[t - off] : 0;
        __syncthreads();
        part[t] = val + add;
        __syncthreads();
    }
    int chunkbase = part[t] - s;
    for (int k = 0; k < CH; ++k) rowoff[base + k] = chunkbase + local[k];
    if (t == 255) rowoff[NROWS] = part[255];   // grand total
}

// ---- 5: ordered emit + padding fill (sigma0, 0, 0) for rows >= total ----
__global__ __launch_bounds__(512) void emit(const unsigned long long* __restrict__ rowbits,
                                            const int* __restrict__ rowoff,
                                            const float* __restrict__ sigma_list,
                                            float* __restrict__ out) {
    int bz = blockIdx.x;                  // (s,y): 0..6655
    int s = bz >> 9;
    int y = bz & 511;
    int t = threadIdx.x;
    __shared__ unsigned long long m[8];
    __shared__ int roff, total;
    if (t < 8) m[t] = rowbits[bz * 8 + t];
    if (t == 0) {
        roff = rowoff[bz];
        total = min(rowoff[NROWS], MAXPEAKS);
    }
    __syncthreads();
    int wid = t >> 6, lane = t & 63;
    unsigned long long mw = m[wid];
    if ((mw >> lane) & 1ull) {
        int rank = 0;
        for (int k = 0; k < wid; ++k) rank += __popcll(m[k]);
        rank += __popcll(mw & ((1ull << lane) - 1ull));
        int pos = roff + rank;
        if (pos < MAXPEAKS) {
            out[pos * 3 + 0] = sigma_list[s];
            out[pos * 3 + 1] = (float)y;
            out[pos * 3 + 2] = (float)t;
        }
    }
    int idx = bz * 512 + t;               // blocks 0..63 cover all 32768 rows
    if (idx < MAXPEAKS && idx >= total) {
        out[idx * 3 + 0] = sigma_list[0];
        out[idx * 3 + 1] = 0.0f;
        out[idx * 3 + 2] = 0.0f;
    }
}

extern "C" void kernel_launch(void* const* d_in, const int* in_sizes, int n_in,
                              void* d_out, int out_size, void* d_ws, size_t ws_size,
                              hipStream_t stream) {
    const float* x     = (const float*)d_in[0];   // [1,1,512,512]
    const float* sigma = (const float*)d_in[2];   // [14]
    float* out = (float*)d_out;                   // [32768,3]

    char* ws = (char*)d_ws;
    float* h                     = (float*)(ws + OFF_H);
    float* dog                   = (float*)(ws + OFF_DOG);
    unsigned long long* rowbits  = (unsigned long long*)(ws + OFF_BITS);
    int* rowcount                = (int*)(ws + OFF_RCNT);
    int* rowoff                  = (int*)(ws + OFF_ROFF);

    hpass<<<dim3(64, 14), 256, 0, stream>>>(x, sigma, h);
    vdog<<<dim3(8, 32, 13), 64, 0, stream>>>(h, sigma, dog);
    detect<<<dim3(64, 13), 512, 0, stream>>>(dog, rowbits, rowcount);
    scan<<<1, 256, 0, stream>>>(rowcount, rowoff);
    emit<<<NROWS, 512, 0, stream>>>(rowbits, rowoff, sigma, out);
}

// Round 4
// 111.773 us; speedup vs baseline: 1.7197x; 1.2451x over previous
//
#include <hip/hip_runtime.h>
#include <hip/hip_bf16.h>

// DifferenceOfGaussians on MI355X — round 4.
// Guard-padded h => unconditional vdog loads (pure fp64 FMA loop);
// scan kernel eliminated (group counts + per-block redundant reduce);
// 4 kernels: hpass, vdog, detect, emit.
//
// Workspace (bytes):
//   OFF_H    : float h[14][640][512]   = 18,350,080  (rows 43..554 = data,
//              rows 0..42 & 555..597 zero guards, 598..639 don't-care)
//   OFF_DOG  : float dog[13][512][512] = 13,631,488
//   OFF_BITS : u64  rowbits[6656][8]   =    425,984
//   OFF_GCNT : int  gcnt[832]          (peaks per 8-row group)
// total ~32.4 MB

#define OFF_H    0
#define OFF_DOG  18350080
#define OFF_BITS 31981568
#define OFF_GCNT 32407552

#define HROWS 640
#define HPAD  43
#define NSIG 13
#define MAXPEAKS 32768

// Build normalized (optionally sign-flipped) weights, zero-padded to 96,
// using one 64-lane wave. Matches reference exp(-(d/(2s))^2) / sum.
__device__ __forceinline__ void make_w(float s, double sgn, double* wl, int lane) {
    int r = (int)(4.0f * s + 0.5f);
    int n = 2 * r + 1;
    double v0 = 0.0, v1 = 0.0;
    double sd = (double)s;
    if (lane < n) {
        double d = (double)(lane - r), q = d / (2.0 * sd);
        v0 = exp(-q * q);
    }
    if (lane + 64 < n) {
        double d = (double)(lane + 64 - r), q = d / (2.0 * sd);
        v1 = exp(-q * q);
    }
    double part = v0 + v1;
    for (int m = 1; m < 64; m <<= 1) part += __shfl_xor(part, m);
    double inv = sgn / part;
    wl[lane] = v0 * inv;
    if (lane + 64 < 96) wl[lane + 64] = v1 * inv;
}

// ---- 1: horizontal blur + guard zeroing; 16 outputs/thread ----
// block 256 = 8 rows x 32 threads; grid (64 rowgroups, 14 planes), heavy first
__global__ __launch_bounds__(256) void hpass(const float* __restrict__ x,
                                             const float* __restrict__ sigma_list,
                                             float* __restrict__ h) {
    const int i = 13 - blockIdx.y;        // heavy plane first
    const int t = threadIdx.x;
    float s = sigma_list[i];
    int r = (int)(4.0f * s + 0.5f);
    int n = 2 * r + 1;
    int nceil = (n + 15) & ~15;

    __shared__ double wl[96];
    if (t < 64) make_w(s, +1.0, wl, t);

    // zero this block's share of the 86 guard rows (64 blocks x 688 = 86*512)
    {
        float* hp = h + i * (HROWS * 512);
        for (int k = t; k < 688; k += 256) {
            int f = blockIdx.x * 688 + k;      // 0..44031
            int g = f >> 9, xc = f & 511;      // g in 0..85
            int row = (g < HPAD) ? g : (g + 512);   // 0..42, 555..597
            hp[row * 512 + xc] = 0.0f;
        }
    }

    // stage 8 zero-padded rows, skewed (addr = p + p/16)
    __shared__ float rowp[8][648];
    int y8 = blockIdx.x * 8;
    for (int rr = 0; rr < 8; ++rr)
        for (int k = t; k < 608; k += 256) {
            int gx = k - 43;
            float val = ((unsigned)gx < 512u) ? x[(y8 + rr) * 512 + gx] : 0.0f;
            rowp[rr][k + (k >> 4)] = val;
        }
    __syncthreads();

    int tsub = t & 31, row = t >> 5;
    int xb = tsub * 16;
    int P0 = 43 - r + xb;
    double acc[16], win[16];
#pragma unroll
    for (int j = 0; j < 16; ++j) acc[j] = 0.0;
#pragma unroll
    for (int sl = 0; sl < 16; ++sl) {
        int p = P0 + sl;
        win[sl] = (double)rowp[row][p + (p >> 4)];
    }
    for (int dc = 0; dc < nceil; dc += 16) {
#pragma unroll
        for (int k = 0; k < 16; ++k) {
            double wd = wl[dc + k];
#pragma unroll
            for (int j = 0; j < 16; ++j)
                acc[j] = fma(wd, win[(k + j) & 15], acc[j]);
            int p = P0 + dc + k + 16;
            win[k] = (double)rowp[row][p + (p >> 4)];
        }
    }
    float* hp = h + (i * HROWS + HPAD + y8 + row) * 512 + xb;
#pragma unroll
    for (int j = 0; j < 16; ++j) hp[j] = (float)acc[j];
}

// Unconditional guarded conv: bp points at padded row (y0 - r + HPAD).
__device__ __forceinline__ void conv_acc(const float* __restrict__ bp,
                                         int nceil, const double* __restrict__ wl,
                                         double (&acc)[16]) {
    double win[16];
#pragma unroll
    for (int sl = 0; sl < 16; ++sl) win[sl] = (double)bp[sl * 512];
    for (int dc = 0; dc < nceil; dc += 16) {
        const float* rp = bp + (dc + 16) * 512;
#pragma unroll
        for (int k = 0; k < 16; ++k) {
            double wd = wl[dc + k];
#pragma unroll
            for (int j = 0; j < 16; ++j)
                acc[j] = fma(wd, win[(k + j) & 15], acc[j]);
            win[k] = (double)rp[k * 512];
        }
    }
}

// ---- 2: vertical blur pair + DoG; 1-wave blocks, heavy plane first ----
// grid (8 x-tiles, 32 y-tiles, 13 planes) = 3328 blocks of 64 threads
__global__ __launch_bounds__(64) void vdog(const float* __restrict__ h,
                                           const float* __restrict__ sigma_list,
                                           float* __restrict__ dog) {
    const int di = 12 - blockIdx.z;
    const int lane = threadIdx.x;
    const int x = blockIdx.x * 64 + lane;
    const int y0 = blockIdx.y * 16;
    float s0 = sigma_list[di], s1 = sigma_list[di + 1];
    int r0 = (int)(4.0f * s0 + 0.5f), n0 = 2 * r0 + 1, nc0 = (n0 + 15) & ~15;
    int r1 = (int)(4.0f * s1 + 0.5f), n1 = 2 * r1 + 1, nc1 = (n1 + 15) & ~15;
    __shared__ double wl0[96], wl1[96];
    make_w(s0, +1.0, wl0, lane);
    make_w(s1, -1.0, wl1, lane);          // negated: acc = conv0 - conv1
    __syncthreads();
    double acc[16];
#pragma unroll
    for (int j = 0; j < 16; ++j) acc[j] = 0.0;
    const float* hp0 = h + di * (HROWS * 512);
    conv_acc(hp0 + (HPAD + y0 - r0) * 512 + x, nc0, wl0, acc);
    const float* hp1 = hp0 + HROWS * 512;
    conv_acc(hp1 + (HPAD + y0 - r1) * 512 + x, nc1, wl1, acc);
    double sg = (double)s0;
    float* dp = dog + (di * 512 + y0) * 512 + x;
#pragma unroll
    for (int j = 0; j < 16; ++j) dp[j * 512] = (float)(acc[j] * sg);
}

// ---- 3: 3x3x3 peak detect; 8-row tile, colmax trick; group counts ----
// grid (64 y-tiles, 13 scales), block 512
__global__ __launch_bounds__(512) void detect(const float* __restrict__ dog,
                                              unsigned long long* __restrict__ rowbits,
                                              int* __restrict__ gcnt) {
    const int s = blockIdx.y;
    const int y0 = blockIdx.x * 8;
    const int group = s * 64 + blockIdx.x;
    const int t = threadIdx.x;
    const int w = t >> 6, lane = t & 63;

    if (s == 0 || s == 12) {
        if (t < 64) rowbits[(s * 512 + y0 + (t >> 3)) * 8 + (t & 7)] = 0ull;
        if (t == 0) gcnt[group] = 0;
        return;
    }

    float pm[10], vcen[8];
#pragma unroll
    for (int k = 0; k < 8; ++k) vcen[k] = 0.0f;
#pragma unroll
    for (int q = 0; q < 10; ++q) {
        int yy = y0 - 1 + q;
        float m = -3.0e38f;
        if ((unsigned)yy < 512u) {
            float a = dog[((s - 1) * 512 + yy) * 512 + t];
            float b = dog[(s * 512 + yy) * 512 + t];
            float c = dog[((s + 1) * 512 + yy) * 512 + t];
            m = fmaxf(a, fmaxf(b, c));
            if (q >= 1 && q <= 8) vcen[q - 1] = b;
        }
        pm[q] = m;
    }
    __shared__ float cml[8][512];
    __shared__ int cnt[8][8];
#pragma unroll
    for (int k = 0; k < 8; ++k)
        cml[k][t] = fmaxf(pm[k], fmaxf(pm[k + 1], pm[k + 2]));
    __syncthreads();
#pragma unroll
    for (int k = 0; k < 8; ++k) {
        int y = y0 + k;
        bool peak = false;
        if (t >= 1 && t <= 510 && y >= 1 && y <= 510) {
            float v = vcen[k];
            if (v > 0.001f) {
                float mx = fmaxf(cml[k][t - 1], fmaxf(cml[k][t], cml[k][t + 1]));
                peak = (v >= mx);          // mx includes v
            }
        }
        unsigned long long m = __ballot(peak);
        if (lane == 0) {
            rowbits[(s * 512 + y) * 8 + w] = m;
            cnt[k][w] = __popcll(m);
        }
    }
    __syncthreads();
    if (t == 0) {
        int c = 0;
#pragma unroll
        for (int k = 0; k < 8; ++k)
#pragma unroll
            for (int q = 0; q < 8; ++q) c += cnt[k][q];
        gcnt[group] = c;
    }
}

// ---- 4: ordered emit + padding fill; per-block redundant group reduce ----
// grid 832 blocks x 512 (block b covers scale b/64, rows (b%64)*8 .. +7)
__global__ __launch_bounds__(512) void emit(const unsigned long long* __restrict__ rowbits,
                                            const int* __restrict__ gcnt,
                                            const float* __restrict__ sigma_list,
                                            float* __restrict__ out) {
    const int b = blockIdx.x;
    const int s = b >> 6;
    const int y0 = (b & 63) * 8;
    const int t = threadIdx.x;
    const int lane = t & 63;

    __shared__ unsigned long long m[64];   // [row k][word q]
    __shared__ int pre[64];                // exclusive word prefix (row-major)
    __shared__ int redA[512], redB[512];

    if (t < 64) m[t] = rowbits[(s * 512 + y0 + (t >> 3)) * 8 + (t & 7)];

    int pa = 0, pb = 0;
    {
        int c0 = (t < 832) ? gcnt[t] : 0;
        int i1 = t + 512;
        int c1 = (i1 < 832) ? gcnt[i1] : 0;
        pb = c0 + c1;
        if (t < b) pa += c0;
        if (i1 < b) pa += c1;
    }
    redA[t] = pa;
    redB[t] = pb;
    __syncthreads();
    for (int off = 256; off > 0; off >>= 1) {
        if (t < off) { redA[t] += redA[t + off]; redB[t] += redB[t + off]; }
        __syncthreads();
    }
    int gbase = redA[0];
    int tot = min(redB[0], MAXPEAKS);

    if (t < 64) {                          // wave-0 exclusive scan of word counts
        int wc = (int)__popcll(m[t]);
        int inc = wc;
        for (int off = 1; off < 64; off <<= 1) {
            int v = __shfl_up(inc, off);
            if (lane >= off) inc += v;
        }
        pre[t] = inc - wc;
    }
    __syncthreads();

#pragma unroll
    for (int k = 0; k < 8; ++k) {
        int widx = k * 8 + (t >> 6);
        unsigned long long mw = m[widx];
        if ((mw >> lane) & 1ull) {
            int pos = gbase + pre[widx] + (int)__popcll(mw & ((1ull << lane) - 1ull));
            if (pos < MAXPEAKS) {
                out[pos * 3 + 0] = sigma_list[s];
                out[pos * 3 + 1] = (float)(y0 + k);
                out[pos * 3 + 2] = (float)t;
            }
        }
    }

    int idx = b * 512 + t;                 // blocks 0..63 cover all 32768 rows
    if (idx < MAXPEAKS && idx >= tot) {
        out[idx * 3 + 0] = sigma_list[0];
        out[idx * 3 + 1] = 0.0f;
        out[idx * 3 + 2] = 0.0f;
    }
}

extern "C" void kernel_launch(void* const* d_in, const int* in_sizes, int n_in,
                              void* d_out, int out_size, void* d_ws, size_t ws_size,
                              hipStream_t stream) {
    const float* x     = (const float*)d_in[0];   // [1,1,512,512]
    const float* sigma = (const float*)d_in[2];   // [14]
    float* out = (float*)d_out;                   // [32768,3]

    char* ws = (char*)d_ws;
    float* h                     = (float*)(ws + OFF_H);
    float* dog                   = (float*)(ws + OFF_DOG);
    unsigned long long* rowbits  = (unsigned long long*)(ws + OFF_BITS);
    int* gcnt                    = (int*)(ws + OFF_GCNT);

    hpass<<<dim3(64, 14), 256, 0, stream>>>(x, sigma, h);
    vdog<<<dim3(8, 32, 13), 64, 0, stream>>>(h, sigma, dog);
    detect<<<dim3(64, 13), 512, 0, stream>>>(dog, rowbits, gcnt);
    emit<<<832, 512, 0, stream>>>(rowbits, gcnt, sigma, out);
}